// Round 1
// baseline (4328.714 us; speedup 1.0000x reference)
//
#include <hip/hip_runtime.h>
#include <math.h>

// ---------------- workspace layout (float offsets) ----------------
// h1 : [16,128,128,128] = 33,554,432 floats
// h2 : [16,256, 64, 64] = 16,777,216 floats
// enorm : 512, hist : 512 (u32), sse : 1
// z lives in d_out[0 .. 4194304) and is overwritten in-place by quantized.
#define H1_OFF     0ull
#define H2_OFF     33554432ull
#define ENORM_OFF  50331648ull
#define HIST_OFF   50332160ull
#define SSE_OFF    50332672ull
// total ws need: 50,332,673 floats = ~201.3 MB

// ================= conv1: 3->128, 4x4 s2 p1, 256->128, ReLU =================
__global__ __launch_bounds__(256) void conv1_k(const float* __restrict__ x,
                                               const float* __restrict__ w,
                                               const float* __restrict__ bias,
                                               float* __restrict__ out) {
  const int tx = threadIdx.x, ty = threadIdx.y;
  const int tile_x = blockIdx.x, tile_y = blockIdx.y, b = blockIdx.z;
  __shared__ float xs[3][34][35];
  const int tid = ty * 16 + tx;
  const int iy0 = tile_y * 32 - 1, ix0 = tile_x * 32 - 1;
  for (int idx = tid; idx < 3 * 1156; idx += 256) {
    int ci = idx / 1156; int rem = idx - ci * 1156;
    int r = rem / 34;    int c = rem - r * 34;
    int iy = iy0 + r, ix = ix0 + c;
    float v = 0.f;
    if (iy >= 0 && iy < 256 && ix >= 0 && ix < 256)
      v = x[((b * 3 + ci) * 256 + iy) * 256 + ix];
    xs[ci][r][c] = v;
  }
  __syncthreads();
  float p[48];
#pragma unroll
  for (int ci = 0; ci < 3; ++ci)
#pragma unroll
    for (int kh = 0; kh < 4; ++kh)
#pragma unroll
      for (int kw = 0; kw < 4; ++kw)
        p[ci * 16 + kh * 4 + kw] = xs[ci][2 * ty + kh][2 * tx + kw];
  const int Y = tile_y * 16 + ty, X = tile_x * 16 + tx;
  for (int co = 0; co < 128; ++co) {
    float acc = bias[co];
#pragma unroll
    for (int t = 0; t < 48; ++t) acc += p[t] * w[co * 48 + t];  // uniform -> s_load
    out[((b * 128 + co) * 128 + Y) * 128 + X] = acc > 0.f ? acc : 0.f;
  }
}

// ================= conv2: 128->256, 4x4 s2 p1, 128->64, ReLU =================
__global__ __launch_bounds__(256) void conv2_k(const float* __restrict__ in,
                                               const float* __restrict__ w,
                                               const float* __restrict__ bias,
                                               float* __restrict__ out) {
  const int tx = threadIdx.x, ty = threadIdx.y;
  const int bid = blockIdx.x;
  const int tile = bid & 15, cb = (bid >> 4) & 7, b = bid >> 7;
  const int tile_y = tile >> 2, tile_x = tile & 3;
  const int co0 = cb * 32;
  __shared__ float xs[8][34][35];
  float acc[32];
#pragma unroll
  for (int u = 0; u < 32; ++u) acc[u] = bias[co0 + u];
  const int tid = ty * 16 + tx;
  const int iy0 = tile_y * 32 - 1, ix0 = tile_x * 32 - 1;
  for (int cc = 0; cc < 16; ++cc) {
    __syncthreads();
    for (int idx = tid; idx < 8 * 1156; idx += 256) {
      int ci = idx / 1156; int rem = idx - ci * 1156;
      int r = rem / 34;    int c = rem - r * 34;
      int iy = iy0 + r, ix = ix0 + c;
      float v = 0.f;
      if (iy >= 0 && iy < 128 && ix >= 0 && ix < 128)
        v = in[((b * 128 + cc * 8 + ci) * 128 + iy) * 128 + ix];
      xs[ci][r][c] = v;
    }
    __syncthreads();
    for (int ci = 0; ci < 8; ++ci) {
      float p[16];
#pragma unroll
      for (int kh = 0; kh < 4; ++kh)
#pragma unroll
        for (int kw = 0; kw < 4; ++kw)
          p[kh * 4 + kw] = xs[ci][2 * ty + kh][2 * tx + kw];
      const float* wp = &w[(co0 * 128 + (cc * 8 + ci)) * 16];  // uniform base
#pragma unroll
      for (int u = 0; u < 32; ++u)
#pragma unroll
        for (int t = 0; t < 16; ++t)
          acc[u] += p[t] * wp[u * 2048 + t];  // uniform -> s_load
    }
  }
  const int Y = tile_y * 16 + ty, X = tile_x * 16 + tx;
#pragma unroll
  for (int u = 0; u < 32; ++u) {
    float v = acc[u];
    out[((b * 256 + co0 + u) * 64 + Y) * 64 + X] = v > 0.f ? v : 0.f;
  }
}

// ================= conv3: 256->64, 3x3 s1 p1, 64->64 (z, no relu) =================
__global__ __launch_bounds__(256) void conv3_k(const float* __restrict__ in,
                                               const float* __restrict__ w,
                                               const float* __restrict__ bias,
                                               float* __restrict__ out) {
  const int tx = threadIdx.x, ty = threadIdx.y;
  const int bid = blockIdx.x;
  const int cb = bid & 1, tile = (bid >> 1) & 15, b = bid >> 5;
  const int tile_y = tile >> 2, tile_x = tile & 3;
  const int co0 = cb * 32;
  __shared__ float xs[8][18][19];
  float acc[32];
#pragma unroll
  for (int u = 0; u < 32; ++u) acc[u] = bias[co0 + u];
  const int tid = ty * 16 + tx;
  const int iy0 = tile_y * 16 - 1, ix0 = tile_x * 16 - 1;
  for (int cc = 0; cc < 32; ++cc) {
    __syncthreads();
    for (int idx = tid; idx < 8 * 324; idx += 256) {
      int ci = idx / 324; int rem = idx - ci * 324;
      int r = rem / 18;   int c = rem - r * 18;
      int iy = iy0 + r, ix = ix0 + c;
      float v = 0.f;
      if (iy >= 0 && iy < 64 && ix >= 0 && ix < 64)
        v = in[((b * 256 + cc * 8 + ci) * 64 + iy) * 64 + ix];
      xs[ci][r][c] = v;
    }
    __syncthreads();
    for (int ci = 0; ci < 8; ++ci) {
      float p[9];
#pragma unroll
      for (int kh = 0; kh < 3; ++kh)
#pragma unroll
        for (int kw = 0; kw < 3; ++kw)
          p[kh * 3 + kw] = xs[ci][ty + kh][tx + kw];
      const float* wp = &w[(co0 * 256 + cc * 8 + ci) * 9];
#pragma unroll
      for (int u = 0; u < 32; ++u)
#pragma unroll
        for (int t = 0; t < 9; ++t)
          acc[u] += p[t] * wp[u * 2304 + t];  // uniform -> s_load
    }
  }
  const int Y = tile_y * 16 + ty, X = tile_x * 16 + tx;
#pragma unroll
  for (int u = 0; u < 32; ++u)
    out[((b * 64 + co0 + u) * 64 + Y) * 64 + X] = acc[u];
}

// ================= embedding norms =================
__global__ void enorm_k(const float* __restrict__ emb, float* __restrict__ enorm) {
  int k = threadIdx.x;
  if (k < 512) {
    float s = 0.f;
#pragma unroll
    for (int d = 0; d < 64; ++d) { float e = emb[k * 64 + d]; s += e * e; }
    enorm[k] = s;
  }
}

// ================= VQ: argmin + quantize(in-place) + hist + sse =================
__global__ __launch_bounds__(256) void vq_k(float* __restrict__ zq,
                                            const float* __restrict__ emb,
                                            const float* __restrict__ enorm,
                                            unsigned* __restrict__ hist,
                                            float* __restrict__ gsse) {
  const int n = blockIdx.x * 256 + threadIdx.x;
  __shared__ unsigned hcnt[512];
  for (int i = threadIdx.x; i < 512; i += 256) hcnt[i] = 0;
  __syncthreads();
  float z[64];
  const float4* zp4 = reinterpret_cast<const float4*>(&zq[(size_t)n * 64]);
#pragma unroll
  for (int d4 = 0; d4 < 16; ++d4) {
    float4 v = zp4[d4];
    z[d4 * 4 + 0] = v.x; z[d4 * 4 + 1] = v.y; z[d4 * 4 + 2] = v.z; z[d4 * 4 + 3] = v.w;
  }
  float best = 1e30f; int bidx = 0;
  for (int k = 0; k < 512; ++k) {
    float dot = 0.f;
    const float* ep = &emb[k * 64];  // uniform -> s_load
#pragma unroll
    for (int d = 0; d < 64; ++d) dot += z[d] * ep[d];
    float dist = enorm[k] - 2.f * dot;  // |z|^2 constant per row: argmin-equivalent
    if (dist < best) { best = dist; bidx = k; }  // strict < : first-min, matches argmin
  }
  atomicAdd(&hcnt[bidx], 1u);
  float sse = 0.f;
  float4* op4 = reinterpret_cast<float4*>(&zq[(size_t)n * 64]);
  const float4* eb4 = reinterpret_cast<const float4*>(&emb[bidx * 64]);
#pragma unroll
  for (int d4 = 0; d4 < 16; ++d4) {
    float4 q = eb4[d4];
    float dx = q.x - z[d4 * 4 + 0], dy = q.y - z[d4 * 4 + 1];
    float dz = q.z - z[d4 * 4 + 2], dw = q.w - z[d4 * 4 + 3];
    sse += dx * dx + dy * dy + dz * dz + dw * dw;
    op4[d4] = q;
  }
#pragma unroll
  for (int off = 32; off > 0; off >>= 1) sse += __shfl_down(sse, off, 64);
  if ((threadIdx.x & 63) == 0) atomicAdd(gsse, sse);
  __syncthreads();
  for (int i = threadIdx.x; i < 512; i += 256)
    if (hcnt[i]) atomicAdd(&hist[i], hcnt[i]);
}

// ================= finalize: vq_loss + perplexity =================
__global__ void fin_k(const unsigned* __restrict__ hist,
                      const float* __restrict__ gsse,
                      float* __restrict__ out) {
  __shared__ float red[512];
  int t = threadIdx.x;
  float p = (float)hist[t] * (1.f / 65536.f);
  red[t] = p * logf(p + 1e-10f);
  __syncthreads();
  for (int s = 256; s > 0; s >>= 1) {
    if (t < s) red[t] += red[t + s];
    __syncthreads();
  }
  if (t == 0) {
    out[4194304] = 1.25f * gsse[0] * (1.f / 4194304.f);  // (1+beta)*mse
    out[4194305] = expf(-red[0]);
  }
}

extern "C" void kernel_launch(void* const* d_in, const int* in_sizes, int n_in,
                              void* d_out, int out_size, void* d_ws, size_t ws_size,
                              hipStream_t stream) {
  const float* x   = (const float*)d_in[0];
  const float* w1  = (const float*)d_in[1];
  const float* b1  = (const float*)d_in[2];
  const float* w2  = (const float*)d_in[3];
  const float* b2  = (const float*)d_in[4];
  const float* w3  = (const float*)d_in[5];
  const float* b3  = (const float*)d_in[6];
  const float* emb = (const float*)d_in[7];
  // decoder weights d_in[8..13] intentionally unused: reference output ignores x_recon

  float* out = (float*)d_out;
  float* ws  = (float*)d_ws;
  float* h1    = ws + H1_OFF;
  float* h2    = ws + H2_OFF;
  float* enorm = ws + ENORM_OFF;
  unsigned* hist = (unsigned*)(ws + HIST_OFF);
  float* gsse  = ws + SSE_OFF;

  // zero the accumulators every call (harness poisons ws once, never re-poisons)
  hipMemsetAsync(ws + HIST_OFF, 0, (512 + 1) * sizeof(float), stream);

  conv1_k<<<dim3(8, 8, 16), dim3(16, 16), 0, stream>>>(x, w1, b1, h1);
  conv2_k<<<dim3(2048), dim3(16, 16), 0, stream>>>(h1, w2, b2, h2);
  conv3_k<<<dim3(512), dim3(16, 16), 0, stream>>>(h2, w3, b3, out);  // z -> d_out
  enorm_k<<<dim3(1), dim3(512), 0, stream>>>(emb, enorm);
  vq_k<<<dim3(256), dim3(256), 0, stream>>>(out, emb, enorm, hist, gsse);
  fin_k<<<dim3(1), dim3(512), 0, stream>>>(hist, gsse, out);
}

// Round 2
// 806.416 us; speedup vs baseline: 5.3678x; 5.3678x over previous
//
#include <hip/hip_runtime.h>
#include <math.h>

// ---------------- workspace layout (u32 offsets) ----------------
#define H1P_OFF    0ull           // [16,128,128,128] packed hi|lo<<16 u32
#define H2P_OFF    33554432ull    // [16,256,64,64]   packed u32
#define W2H_OFF    50331648ull    // 524288 u16 (262144 u32)
#define W2L_OFF    50593792ull
#define W3H_OFF    50855936ull    // 147456 u16 (73728 u32)
#define W3L_OFF    50929664ull
#define ENORM_OFF  51003392ull
#define HIST_OFF   51003904ull
#define SSE_OFF    51004416ull
// total ~204 MB

typedef __attribute__((ext_vector_type(8))) short bf16x8;
typedef __attribute__((ext_vector_type(4))) float f32x4;

__device__ inline unsigned short f2bf(float f) {
  unsigned u = __builtin_bit_cast(unsigned, f);
  unsigned r = (u + 0x7fffu + ((u >> 16) & 1u)) >> 16;   // RNE
  return (unsigned short)r;
}
__device__ inline float bf2f(unsigned short h) {
  return __builtin_bit_cast(float, (unsigned)h << 16);
}
__device__ inline unsigned packsplit(float v) {
  unsigned short h = f2bf(v);
  unsigned short l = f2bf(v - bf2f(h));
  return (unsigned)h | ((unsigned)l << 16);
}

// ================= weight split: fp32 -> (hi,lo) bf16 arrays =================
__global__ void split_w_k(const float* __restrict__ w, unsigned short* __restrict__ wh,
                          unsigned short* __restrict__ wl, int n) {
  int i = blockIdx.x * 256 + threadIdx.x;
  if (i < n) {
    float v = w[i];
    unsigned short h = f2bf(v);
    wh[i] = h;
    wl[i] = f2bf(v - bf2f(h));
  }
}

// ================= conv1: 3->128, 4x4 s2 p1, fp32 vector, packed-split out =================
__global__ __launch_bounds__(256) void conv1_k(const float* __restrict__ x,
                                               const float* __restrict__ w,
                                               const float* __restrict__ bias,
                                               unsigned* __restrict__ out) {
  const int tx = threadIdx.x, ty = threadIdx.y;
  const int tile_x = blockIdx.x, tile_y = blockIdx.y, b = blockIdx.z;
  __shared__ float xs[3][34][35];
  const int tid = ty * 16 + tx;
  const int iy0 = tile_y * 32 - 1, ix0 = tile_x * 32 - 1;
  for (int idx = tid; idx < 3 * 1156; idx += 256) {
    int ci = idx / 1156; int rem = idx - ci * 1156;
    int r = rem / 34;    int c = rem - r * 34;
    int iy = iy0 + r, ix = ix0 + c;
    float v = 0.f;
    if (iy >= 0 && iy < 256 && ix >= 0 && ix < 256)
      v = x[((b * 3 + ci) * 256 + iy) * 256 + ix];
    xs[ci][r][c] = v;
  }
  __syncthreads();
  float p[48];
#pragma unroll
  for (int ci = 0; ci < 3; ++ci)
#pragma unroll
    for (int kh = 0; kh < 4; ++kh)
#pragma unroll
      for (int kw = 0; kw < 4; ++kw)
        p[ci * 16 + kh * 4 + kw] = xs[ci][2 * ty + kh][2 * tx + kw];
  const int Y = tile_y * 16 + ty, X = tile_x * 16 + tx;
  for (int co = 0; co < 128; ++co) {
    float acc = bias[co];
#pragma unroll
    for (int t = 0; t < 48; ++t) acc += p[t] * w[co * 48 + t];  // uniform -> s_load
    float v = acc > 0.f ? acc : 0.f;
    out[((b * 128 + co) * 128 + Y) * 128 + X] = packsplit(v);
  }
}

// ============ implicit-GEMM conv via split-bf16 MFMA (16x16x32) ============
// inp packed u32 (hi|lo<<16), weights pre-split wh/wl laid out [co][ci*KW*KW + kh*KW + kw]
// M-tile = 64 = OW (one output row per block); N = OC (full); K = IC*KW*KW, steps of 32.
// MFMA operand swap: arg0 = weight frag (row side = co), arg1 = act frag (col side = x).
template <int IC, int KW, int S, int P, int OC, int IH, int IW, bool RELU, bool SPLIT_OUT>
__global__ __launch_bounds__(256) void convmm_k(const unsigned* __restrict__ inp,
                                                const unsigned short* __restrict__ wh,
                                                const unsigned short* __restrict__ wl,
                                                const float* __restrict__ bias,
                                                unsigned* __restrict__ outp,
                                                float* __restrict__ outf) {
  constexpr int KHW = KW * KW;
  constexpr int K = IC * KHW;
  constexpr int KSTEPS = K / 32;
  static_assert(K % 32 == 0, "K must be multiple of 32");
  constexpr int NFRAG = OC / 64;          // per-wave 16-col n fragments
  constexpr int LDB = 40;                  // padded row stride (u16) for LDS tiles

  __shared__ unsigned short a_h[64 * LDB], a_l[64 * LDB];
  __shared__ unsigned short b_h[OC * LDB], b_l[OC * LDB];

  const int tid = threadIdx.x;
  const int lane = tid & 63, wv = tid >> 6;
  const int bb = blockIdx.x >> 6;          // batch
  const int y = blockIdx.x & 63;           // output row (OH = 64)

  f32x4 acc[NFRAG][4];
#pragma unroll
  for (int nf = 0; nf < NFRAG; ++nf)
#pragma unroll
    for (int xf = 0; xf < 4; ++xf) acc[nf][xf] = (f32x4){0.f, 0.f, 0.f, 0.f};

  const int xx = tid >> 2;                 // A-stage: output x handled by this thread
  const int kkb = (tid & 3) * 8;           // A-stage: kk sub-block
  const int ko = (lane >> 4) * 8;          // frag k offset
  const int rsel = lane & 15;

#pragma unroll 1
  for (int ks = 0; ks < KSTEPS; ++ks) {
    const int kk0 = ks * 32;
    __syncthreads();
    // ---- stage A (im2col gather of packed input) ----
    {
      unsigned hw[4] = {0, 0, 0, 0}, lw[4] = {0, 0, 0, 0};
#pragma unroll
      for (int j = 0; j < 8; ++j) {
        int k = kk0 + kkb + j;
        int ci = k / KHW; int r = k - ci * KHW;
        int kh = r / KW;  int kw2 = r - kh * KW;
        int iy = y * S + kh - P, ix = xx * S + kw2 - P;
        unsigned v = 0;
        if ((unsigned)iy < (unsigned)IH && (unsigned)ix < (unsigned)IW)
          v = inp[((bb * IC + ci) * IH + iy) * IW + ix];
        hw[j >> 1] |= (v & 0xffffu) << ((j & 1) * 16);
        lw[j >> 1] |= (v >> 16) << ((j & 1) * 16);
      }
      *(uint4*)&a_h[xx * LDB + kkb] = make_uint4(hw[0], hw[1], hw[2], hw[3]);
      *(uint4*)&a_l[xx * LDB + kkb] = make_uint4(lw[0], lw[1], lw[2], lw[3]);
    }
    // ---- stage B (pre-split weights, layout already [co][k]) ----
    if constexpr (OC == 256) {
      const uint4* sh = (const uint4*)&wh[(size_t)tid * K + kk0];
      const uint4* sl = (const uint4*)&wl[(size_t)tid * K + kk0];
      uint4* dh = (uint4*)&b_h[tid * LDB];
      uint4* dl = (uint4*)&b_l[tid * LDB];
#pragma unroll
      for (int q = 0; q < 4; ++q) { dh[q] = sh[q]; dl[q] = sl[q]; }
    } else {  // OC == 64
      int n = tid & 63, q = tid >> 6;
      *(uint4*)&b_h[n * LDB + q * 8] = *(const uint4*)&wh[(size_t)n * K + kk0 + q * 8];
      *(uint4*)&b_l[n * LDB + q * 8] = *(const uint4*)&wl[(size_t)n * K + kk0 + q * 8];
    }
    __syncthreads();
    // ---- fragments + MFMA ----
    bf16x8 af_h[4], af_l[4];
#pragma unroll
    for (int xf = 0; xf < 4; ++xf) {
      af_h[xf] = *(const bf16x8*)&a_h[(xf * 16 + rsel) * LDB + ko];
      af_l[xf] = *(const bf16x8*)&a_l[(xf * 16 + rsel) * LDB + ko];
    }
#pragma unroll
    for (int nf = 0; nf < NFRAG; ++nf) {
      bf16x8 wf_h = *(const bf16x8*)&b_h[(wv * (OC / 4) + nf * 16 + rsel) * LDB + ko];
      bf16x8 wf_l = *(const bf16x8*)&b_l[(wv * (OC / 4) + nf * 16 + rsel) * LDB + ko];
#pragma unroll
      for (int xf = 0; xf < 4; ++xf) {
        acc[nf][xf] = __builtin_amdgcn_mfma_f32_16x16x32_bf16(wf_h, af_h[xf], acc[nf][xf], 0, 0, 0);
        acc[nf][xf] = __builtin_amdgcn_mfma_f32_16x16x32_bf16(wf_h, af_l[xf], acc[nf][xf], 0, 0, 0);
        acc[nf][xf] = __builtin_amdgcn_mfma_f32_16x16x32_bf16(wf_l, af_h[xf], acc[nf][xf], 0, 0, 0);
      }
    }
  }
  // ---- epilogue: D row = n (lane>>4)*4+r, col = x (lane&15) -> 64B-contiguous stores ----
#pragma unroll
  for (int nf = 0; nf < NFRAG; ++nf) {
    int nbase = wv * (OC / 4) + nf * 16 + (lane >> 4) * 4;
#pragma unroll
    for (int xf = 0; xf < 4; ++xf) {
      int xo = xf * 16 + (lane & 15);
      size_t o = (((size_t)bb * OC + nbase) * 64 + y) * 64 + xo;
#pragma unroll
      for (int r = 0; r < 4; ++r) {
        float v = acc[nf][xf][r] + bias[nbase + r];
        if (RELU) v = fmaxf(v, 0.f);
        if (SPLIT_OUT) outp[o + (size_t)r * 4096] = packsplit(v);
        else           outf[o + (size_t)r * 4096] = v;
      }
    }
  }
}

// ================= embedding norms =================
__global__ void enorm_k(const float* __restrict__ emb, float* __restrict__ enorm) {
  int k = threadIdx.x;
  if (k < 512) {
    float s = 0.f;
#pragma unroll
    for (int d = 0; d < 64; ++d) { float e = emb[k * 64 + d]; s += e * e; }
    enorm[k] = s;
  }
}

// ================= VQ: argmin + quantize(in-place) + hist + sse =================
__global__ __launch_bounds__(256) void vq_k(float* __restrict__ zq,
                                            const float* __restrict__ emb,
                                            const float* __restrict__ enorm,
                                            unsigned* __restrict__ hist,
                                            float* __restrict__ gsse) {
  const int n = blockIdx.x * 256 + threadIdx.x;
  __shared__ unsigned hcnt[512];
  for (int i = threadIdx.x; i < 512; i += 256) hcnt[i] = 0;
  __syncthreads();
  float z[64];
  const float4* zp4 = reinterpret_cast<const float4*>(&zq[(size_t)n * 64]);
#pragma unroll
  for (int d4 = 0; d4 < 16; ++d4) {
    float4 v = zp4[d4];
    z[d4 * 4 + 0] = v.x; z[d4 * 4 + 1] = v.y; z[d4 * 4 + 2] = v.z; z[d4 * 4 + 3] = v.w;
  }
  float best = 1e30f; int bidx = 0;
  for (int k = 0; k < 512; ++k) {
    float dot = 0.f;
    const float* ep = &emb[k * 64];  // uniform -> s_load
#pragma unroll
    for (int d = 0; d < 64; ++d) dot += z[d] * ep[d];
    float dist = enorm[k] - 2.f * dot;
    if (dist < best) { best = dist; bidx = k; }  // strict < : first-min == argmin
  }
  atomicAdd(&hcnt[bidx], 1u);
  float sse = 0.f;
  float4* op4 = reinterpret_cast<float4*>(&zq[(size_t)n * 64]);
  const float4* eb4 = reinterpret_cast<const float4*>(&emb[bidx * 64]);
#pragma unroll
  for (int d4 = 0; d4 < 16; ++d4) {
    float4 q = eb4[d4];
    float dx = q.x - z[d4 * 4 + 0], dy = q.y - z[d4 * 4 + 1];
    float dz = q.z - z[d4 * 4 + 2], dw = q.w - z[d4 * 4 + 3];
    sse += dx * dx + dy * dy + dz * dz + dw * dw;
    op4[d4] = q;
  }
#pragma unroll
  for (int off = 32; off > 0; off >>= 1) sse += __shfl_down(sse, off, 64);
  if ((threadIdx.x & 63) == 0) atomicAdd(gsse, sse);
  __syncthreads();
  for (int i = threadIdx.x; i < 512; i += 256)
    if (hcnt[i]) atomicAdd(&hist[i], hcnt[i]);
}

// ================= finalize =================
__global__ void fin_k(const unsigned* __restrict__ hist,
                      const float* __restrict__ gsse,
                      float* __restrict__ out) {
  __shared__ float red[512];
  int t = threadIdx.x;
  float p = (float)hist[t] * (1.f / 65536.f);
  red[t] = p * logf(p + 1e-10f);
  __syncthreads();
  for (int s = 256; s > 0; s >>= 1) {
    if (t < s) red[t] += red[t + s];
    __syncthreads();
  }
  if (t == 0) {
    out[4194304] = 1.25f * gsse[0] * (1.f / 4194304.f);
    out[4194305] = expf(-red[0]);
  }
}

extern "C" void kernel_launch(void* const* d_in, const int* in_sizes, int n_in,
                              void* d_out, int out_size, void* d_ws, size_t ws_size,
                              hipStream_t stream) {
  const float* x   = (const float*)d_in[0];
  const float* w1  = (const float*)d_in[1];
  const float* b1  = (const float*)d_in[2];
  const float* w2  = (const float*)d_in[3];
  const float* b2  = (const float*)d_in[4];
  const float* w3  = (const float*)d_in[5];
  const float* b3  = (const float*)d_in[6];
  const float* emb = (const float*)d_in[7];
  // decoder weights unused: reference output ignores x_recon

  float* out = (float*)d_out;
  unsigned* wsu = (unsigned*)d_ws;
  unsigned* h1p = wsu + H1P_OFF;
  unsigned* h2p = wsu + H2P_OFF;
  unsigned short* w2h = (unsigned short*)(wsu + W2H_OFF);
  unsigned short* w2l = (unsigned short*)(wsu + W2L_OFF);
  unsigned short* w3h = (unsigned short*)(wsu + W3H_OFF);
  unsigned short* w3l = (unsigned short*)(wsu + W3L_OFF);
  float* enorm = (float*)(wsu + ENORM_OFF);
  unsigned* hist = wsu + HIST_OFF;
  float* gsse = (float*)(wsu + SSE_OFF);

  hipMemsetAsync(wsu + HIST_OFF, 0, (512 + 1) * sizeof(unsigned), stream);

  split_w_k<<<dim3(2048), dim3(256), 0, stream>>>(w2, w2h, w2l, 524288);
  split_w_k<<<dim3(576),  dim3(256), 0, stream>>>(w3, w3h, w3l, 147456);
  enorm_k<<<dim3(1), dim3(512), 0, stream>>>(emb, enorm);

  conv1_k<<<dim3(8, 8, 16), dim3(16, 16), 0, stream>>>(x, w1, b1, h1p);
  // conv2: 128->256, 4x4 s2 p1, in 128x128 -> out 64x64, ReLU, split-packed out
  convmm_k<128, 4, 2, 1, 256, 128, 128, true, true>
      <<<dim3(1024), dim3(256), 0, stream>>>(h1p, w2h, w2l, b2, h2p, nullptr);
  // conv3: 256->64, 3x3 s1 p1, 64x64 -> 64x64, no relu, fp32 z -> d_out
  convmm_k<256, 3, 1, 1, 64, 64, 64, false, false>
      <<<dim3(1024), dim3(256), 0, stream>>>(h2p, w3h, w3l, b3, nullptr, out);

  vq_k<<<dim3(256), dim3(256), 0, stream>>>(out, emb, enorm, hist, gsse);
  fin_k<<<dim3(1), dim3(512), 0, stream>>>(hist, gsse, out);
}

// Round 3
// 675.987 us; speedup vs baseline: 6.4035x; 1.1929x over previous
//
#include <hip/hip_runtime.h>
#include <math.h>

typedef __attribute__((ext_vector_type(8))) short bf16x8;
typedef __attribute__((ext_vector_type(4))) float f32x4;
typedef __attribute__((ext_vector_type(4))) unsigned u32x4;

// ---------------- workspace layout (u32 offsets) ----------------
// h1p : [16][128][130][132] packed u32 (halo-padded)  = 35,143,680
// h2p : [16][256][66][68]   packed u32 (halo-padded)  = 18,382,848
// wp2 : [256][2048] packed  = 524,288
// wp3 : [64][3072]  packed (kw padded to 4, zeros)    = 196,608
#define H1P_OFF  0ull
#define H2P_OFF  35143680ull
#define WP2_OFF  53526528ull
#define WP3_OFF  54050816ull
#define EN_OFF   54247424ull
#define HIST_OFF 54247936ull
#define SSE_OFF  54248448ull
// total ~217 MB

__device__ inline unsigned short f2bf(float f) {
  unsigned u = __builtin_bit_cast(unsigned, f);
  return (unsigned short)((u + 0x7fffu + ((u >> 16) & 1u)) >> 16);  // RNE
}
__device__ inline float bf2f(unsigned short h) {
  return __builtin_bit_cast(float, (unsigned)h << 16);
}
__device__ inline unsigned packsplit(float v) {
  unsigned short h = f2bf(v);
  unsigned short l = f2bf(v - bf2f(h));
  return (unsigned)h | ((unsigned)l << 16);
}
__device__ inline void gload_lds16(const void* g, void* l) {
  __builtin_amdgcn_global_load_lds((const __attribute__((address_space(1))) void*)g,
                                   (__attribute__((address_space(3))) void*)l, 16, 0, 0);
}
__device__ inline int swz(int row, int g) {  // byte offset in a [rows][32 u32] tile
  return ((row << 7) + (g << 4)) ^ ((row & 7) << 4);
}
#define SEL_HI 0x05040100u
#define SEL_LO 0x07060302u
__device__ inline bf16x8 mkfrag(const u32x4 p, const u32x4 q, unsigned sel) {
  u32x4 r;
  r[0] = __builtin_amdgcn_perm(p[1], p[0], sel);
  r[1] = __builtin_amdgcn_perm(p[3], p[2], sel);
  r[2] = __builtin_amdgcn_perm(q[1], q[0], sel);
  r[3] = __builtin_amdgcn_perm(q[3], q[2], sel);
  return __builtin_bit_cast(bf16x8, r);
}

// ================= weight prep =================
__global__ void pack_w2_k(const float* __restrict__ w, unsigned* __restrict__ wp) {
  int i = blockIdx.x * 256 + threadIdx.x;
  if (i < 524288) wp[i] = packsplit(w[i]);   // layout already [co][ci*16+kh*4+kw]
}
__global__ void pack_w3_k(const float* __restrict__ w, unsigned* __restrict__ wp) {
  int i = blockIdx.x * 256 + threadIdx.x;
  if (i >= 196608) return;
  int co = i / 3072, r = i - co * 3072;
  int ci = r / 12, rb = r - ci * 12, kh = rb >> 2, kw = rb & 3;
  wp[i] = (kw < 3) ? packsplit(w[((co * 256 + ci) * 3 + kh) * 3 + kw]) : 0u;
}

// ================= halo zeroing for padded activation planes =================
__global__ void halo_k(unsigned* __restrict__ h1p, unsigned* __restrict__ h2p) {
  int i = blockIdx.x * 256 + threadIdx.x;
  if (i < 2048 * 520) {           // h1p: 2048 planes x 520 halo cells
    int p = i / 520, c = i - p * 520; int r, cc;
    if (c < 132)      { r = 0;   cc = c; }
    else if (c < 264) { r = 129; cc = c - 132; }
    else if (c < 392) { r = c - 264 + 1; cc = 0; }
    else              { r = c - 392 + 1; cc = 129; }
    h1p[(size_t)p * 130 * 132 + r * 132 + cc] = 0u;
  } else {
    int j = i - 2048 * 520;
    if (j >= 4096 * 328) return;  // h2p: 4096 planes x 328 halo cells
    int p = j / 328, c = j - p * 328; int r, cc;
    if (c < 68)       { r = 0;  cc = c; }
    else if (c < 136) { r = 65; cc = c - 68; }
    else { int c2 = c - 136; int which = c2 >> 6; r = 1 + (c2 & 63);
           cc = (which == 0) ? 0 : (which == 1 ? 65 : 66); }
    h2p[(size_t)p * 66 * 68 + r * 68 + cc] = 0u;
  }
}

// ================= conv1: 3->128, 4x4 s2 p1, fp32 vector, padded packed out ====
__global__ __launch_bounds__(256) void conv1_k(const float* __restrict__ x,
                                               const float* __restrict__ w,
                                               const float* __restrict__ bias,
                                               unsigned* __restrict__ out) {
  const int tx = threadIdx.x, ty = threadIdx.y;
  const int tile_x = blockIdx.x, tile_y = blockIdx.y, b = blockIdx.z;
  __shared__ float xs[3][34][35];
  const int tid = ty * 16 + tx;
  const int iy0 = tile_y * 32 - 1, ix0 = tile_x * 32 - 1;
  for (int idx = tid; idx < 3 * 1156; idx += 256) {
    int ci = idx / 1156; int rem = idx - ci * 1156;
    int r = rem / 34;    int c = rem - r * 34;
    int iy = iy0 + r, ix = ix0 + c;
    float v = 0.f;
    if (iy >= 0 && iy < 256 && ix >= 0 && ix < 256)
      v = x[((b * 3 + ci) * 256 + iy) * 256 + ix];
    xs[ci][r][c] = v;
  }
  __syncthreads();
  float p[48];
#pragma unroll
  for (int ci = 0; ci < 3; ++ci)
#pragma unroll
    for (int kh = 0; kh < 4; ++kh)
#pragma unroll
      for (int kw = 0; kw < 4; ++kw)
        p[ci * 16 + kh * 4 + kw] = xs[ci][2 * ty + kh][2 * tx + kw];
  const int Y = tile_y * 16 + ty, X = tile_x * 16 + tx;
  for (int co = 0; co < 128; ++co) {
    float acc = bias[co];
#pragma unroll
    for (int t = 0; t < 48; ++t) acc += p[t] * w[co * 48 + t];  // uniform -> s_load
    float v = acc > 0.f ? acc : 0.f;
    out[((size_t)(b * 128 + co) * 130 + (Y + 1)) * 132 + (X + 1)] = packsplit(v);
  }
}

// ====== pipelined implicit-GEMM conv, split-bf16 MFMA, packed-u32 LDS =========
// M=64 (one out row/block), N=OC, K=IC*KHW in steps of 32.
// B staged via global_load_lds (swizzled source), A reg-staged from halo-padded input.
template <int IC, int KHW, int OC, int IHP, int IWP, int S,
          int OSR, int OSP, int OPAD, bool SPLIT_OUT>
__global__ __launch_bounds__(256, 2) void convmm_k(const unsigned* __restrict__ inp,
                                                   const unsigned* __restrict__ wp,
                                                   const float* __restrict__ bias,
                                                   unsigned* __restrict__ outp,
                                                   float* __restrict__ outf) {
  constexpr int K = IC * KHW;
  constexpr int KSTEPS = K / 32;
  constexpr int NFRAG = OC / 64;
  constexpr int BROUNDS = OC / 32;       // (OC*128B)/4KB DMA rounds
  constexpr int TOT = 4 + BROUNDS;       // vmem issues per step (A:4 + B:BROUNDS)
  constexpr int MIDW = TOT - 4;          // wait leaving only next-B outstanding
  constexpr int ABYTES = 8192;           // 64 rows x 128B
  constexpr int BBYTES = OC * 128;
  constexpr int BUFB = ABYTES + BBYTES;
  __shared__ char smem[2 * BUFB];

  const int tid = threadIdx.x, l = tid & 63, wv = tid >> 6;
  const int bb = blockIdx.x >> 6, y = blockIdx.x & 63;
  const int rsel = l & 15, g0 = (l >> 4) * 2;

  // ---- A staging mapping (thread covers 2 rows: arow0, arow0+32) ----
  const int arow0 = wv * 8 + (l >> 3);
  const int as = l & 7;
  const int cgp = as ^ (l >> 3);          // swizzled logical k-group
  const unsigned* aptr0;
  const unsigned* aptr1;
  if constexpr (KHW == 16) {
    const int kh = cgp & 3, cis = cgp >> 2;
    aptr0 = inp + (((size_t)bb * IC + cis) * IHP + (S * y + kh)) * IWP + S * arow0;
    aptr1 = aptr0 + (size_t)S * 32;
  }
  // ---- B per-lane u32 offsets (row*K + swizzled col-group) ----
  int offB[BROUNDS];
#pragma unroll
  for (int i = 0; i < BROUNDS; ++i) {
    int row = i * 32 + wv * 8 + (l >> 3);
    int cg = (l & 7) ^ (row & 7);
    offB[i] = row * K + cg * 4;
  }

  f32x4 acc[NFRAG][4];
#pragma unroll
  for (int nf = 0; nf < NFRAG; ++nf)
#pragma unroll
    for (int xf = 0; xf < 4; ++xf) acc[nf][xf] = (f32x4){0.f, 0.f, 0.f, 0.f};

  u32x4 av0, av1;

  auto issueA = [&](int ks) {
    if constexpr (KHW == 16) {
      av0[0] = aptr0[0]; av0[1] = aptr0[1]; av0[2] = aptr0[2]; av0[3] = aptr0[3];
      av1[0] = aptr1[0]; av1[1] = aptr1[1]; av1[2] = aptr1[2]; av1[3] = aptr1[3];
      aptr0 += (size_t)2 * IHP * IWP;     // ci advances by 32/KHW = 2 per step
      aptr1 += (size_t)2 * IHP * IWP;
    } else {                               // KHW == 12 (conv3)
      int k = ks * 32 + cgp * 4;
      int ci = (k * 5462) >> 16;           // k/12 for k < ~9000
      int rb = k - ci * 12;
      int kh = rb >> 2;
      const unsigned* p = inp + (((size_t)bb * IC + ci) * IHP + (y + kh)) * IWP + arow0;
      av0[0] = p[0]; av0[1] = p[1]; av0[2] = p[2]; av0[3] = p[3];
      const unsigned* q = p + 32;
      av1[0] = q[0]; av1[1] = q[1]; av1[2] = q[2]; av1[3] = q[3];
    }
  };
  auto issueB = [&](int buf, int ks) {
    char* base = smem + buf * BUFB + ABYTES + wv * 1024;
    const unsigned* wsrc = wp + ks * 32;
#pragma unroll
    for (int i = 0; i < BROUNDS; ++i)
      gload_lds16(wsrc + offB[i], base + i * 4096);
  };
  auto writeA = [&](int buf) {
    char* base = smem + buf * BUFB;
    *(u32x4*)(base + (arow0 << 7) + (as << 4)) = av0;
    *(u32x4*)(base + ((arow0 + 32) << 7) + (as << 4)) = av1;
  };

  // ---- prologue: stage tile 0 ----
  issueA(0);
  issueB(0, 0);
  asm volatile("s_waitcnt vmcnt(%0)" :: "n"(MIDW) : "memory");
  writeA(0);
  asm volatile("s_waitcnt lgkmcnt(0)" ::: "memory");

#pragma unroll 1
  for (int ks = 0; ks < KSTEPS; ++ks) {
    const int cur = ks & 1;
    const bool has = (ks + 1 < KSTEPS);
    if (has) {
      issueA(ks + 1);
      issueB(cur ^ 1, ks + 1);
      asm volatile("s_waitcnt vmcnt(%0)" :: "n"(TOT) : "memory");
    } else {
      asm volatile("s_waitcnt vmcnt(0)" ::: "memory");
    }
    __builtin_amdgcn_s_barrier();
    asm volatile("" ::: "memory");

    const char* bA = smem + cur * BUFB;
    const char* bB = bA + ABYTES;
    u32x4 ar[4][2];
#pragma unroll
    for (int xf = 0; xf < 4; ++xf) {
      int row = xf * 16 + rsel;
      ar[xf][0] = *(const u32x4*)(bA + swz(row, g0));
      ar[xf][1] = *(const u32x4*)(bA + swz(row, g0 + 1));
    }
    u32x4 br[NFRAG][2];
#pragma unroll
    for (int nf = 0; nf < NFRAG; ++nf) {
      int row = wv * (OC / 4) + nf * 16 + rsel;
      br[nf][0] = *(const u32x4*)(bB + swz(row, g0));
      br[nf][1] = *(const u32x4*)(bB + swz(row, g0 + 1));
    }
    if (has) {
      asm volatile("s_waitcnt vmcnt(%0)" :: "n"(MIDW) : "memory");
      writeA(cur ^ 1);
    }
    bf16x8 ah[4], al[4];
#pragma unroll
    for (int xf = 0; xf < 4; ++xf) {
      ah[xf] = mkfrag(ar[xf][0], ar[xf][1], SEL_HI);
      al[xf] = mkfrag(ar[xf][0], ar[xf][1], SEL_LO);
    }
#pragma unroll
    for (int nf = 0; nf < NFRAG; ++nf) {
      bf16x8 wh = mkfrag(br[nf][0], br[nf][1], SEL_HI);
      bf16x8 wl = mkfrag(br[nf][0], br[nf][1], SEL_LO);
#pragma unroll
      for (int xf = 0; xf < 4; ++xf) {
        acc[nf][xf] = __builtin_amdgcn_mfma_f32_16x16x32_bf16(wh, ah[xf], acc[nf][xf], 0, 0, 0);
        acc[nf][xf] = __builtin_amdgcn_mfma_f32_16x16x32_bf16(wh, al[xf], acc[nf][xf], 0, 0, 0);
        acc[nf][xf] = __builtin_amdgcn_mfma_f32_16x16x32_bf16(wl, ah[xf], acc[nf][xf], 0, 0, 0);
      }
    }
    asm volatile("s_waitcnt lgkmcnt(0)" ::: "memory");
    __builtin_amdgcn_s_barrier();
    asm volatile("" ::: "memory");
  }

  // ---- epilogue: D col = lane&15 -> x, row = (lane>>4)*4+r -> co ----
#pragma unroll
  for (int nf = 0; nf < NFRAG; ++nf) {
    int n0 = wv * (OC / 4) + nf * 16 + (l >> 4) * 4;
#pragma unroll
    for (int xf = 0; xf < 4; ++xf) {
      int xo = xf * 16 + rsel;
#pragma unroll
      for (int r = 0; r < 4; ++r) {
        float v = acc[nf][xf][r] + bias[n0 + r];
        if constexpr (SPLIT_OUT) {  // conv2: ReLU + packed padded store
          if (v < 0.f) v = 0.f;
          outp[((size_t)bb * OC + n0 + r) * OSP + (size_t)(y + OPAD) * OSR + (xo + OPAD)] =
              packsplit(v);
        } else {                    // conv3: fp32 dense z
          outf[((size_t)bb * OC + n0 + r) * OSP + (size_t)y * OSR + xo] = v;
        }
      }
    }
  }
}

// ================= embedding norms =================
__global__ void enorm_k(const float* __restrict__ emb, float* __restrict__ enorm) {
  int k = threadIdx.x;
  if (k < 512) {
    float s = 0.f;
#pragma unroll
    for (int d = 0; d < 64; ++d) { float e = emb[k * 64 + d]; s += e * e; }
    enorm[k] = s;
  }
}

// ================= VQ: argmin + quantize(in-place) + hist + sse =================
__global__ __launch_bounds__(256) void vq_k(float* __restrict__ zq,
                                            const float* __restrict__ emb,
                                            const float* __restrict__ enorm,
                                            unsigned* __restrict__ hist,
                                            float* __restrict__ gsse) {
  const int n = blockIdx.x * 256 + threadIdx.x;
  __shared__ unsigned hcnt[512];
  for (int i = threadIdx.x; i < 512; i += 256) hcnt[i] = 0;
  __syncthreads();
  float z[64];
  const float4* zp4 = reinterpret_cast<const float4*>(&zq[(size_t)n * 64]);
#pragma unroll
  for (int d4 = 0; d4 < 16; ++d4) {
    float4 v = zp4[d4];
    z[d4 * 4 + 0] = v.x; z[d4 * 4 + 1] = v.y; z[d4 * 4 + 2] = v.z; z[d4 * 4 + 3] = v.w;
  }
  float best = 1e30f; int bidx = 0;
  for (int k = 0; k < 512; ++k) {
    float dot = 0.f;
    const float* ep = &emb[k * 64];  // uniform -> s_load
#pragma unroll
    for (int d = 0; d < 64; ++d) dot += z[d] * ep[d];
    float dist = enorm[k] - 2.f * dot;
    if (dist < best) { best = dist; bidx = k; }  // strict < : first-min == argmin
  }
  atomicAdd(&hcnt[bidx], 1u);
  float sse = 0.f;
  float4* op4 = reinterpret_cast<float4*>(&zq[(size_t)n * 64]);
  const float4* eb4 = reinterpret_cast<const float4*>(&emb[bidx * 64]);
#pragma unroll
  for (int d4 = 0; d4 < 16; ++d4) {
    float4 q = eb4[d4];
    float dx = q.x - z[d4 * 4 + 0], dy = q.y - z[d4 * 4 + 1];
    float dz = q.z - z[d4 * 4 + 2], dw = q.w - z[d4 * 4 + 3];
    sse += dx * dx + dy * dy + dz * dz + dw * dw;
    op4[d4] = q;
  }
#pragma unroll
  for (int off = 32; off > 0; off >>= 1) sse += __shfl_down(sse, off, 64);
  if ((threadIdx.x & 63) == 0) atomicAdd(gsse, sse);
  __syncthreads();
  for (int i = threadIdx.x; i < 512; i += 256)
    if (hcnt[i]) atomicAdd(&hist[i], hcnt[i]);
}

// ================= finalize =================
__global__ void fin_k(const unsigned* __restrict__ hist,
                      const float* __restrict__ gsse,
                      float* __restrict__ out) {
  __shared__ float red[512];
  int t = threadIdx.x;
  float p = (float)hist[t] * (1.f / 65536.f);
  red[t] = p * logf(p + 1e-10f);
  __syncthreads();
  for (int s = 256; s > 0; s >>= 1) {
    if (t < s) red[t] += red[t + s];
    __syncthreads();
  }
  if (t == 0) {
    out[4194304] = 1.25f * gsse[0] * (1.f / 4194304.f);
    out[4194305] = expf(-red[0]);
  }
}

extern "C" void kernel_launch(void* const* d_in, const int* in_sizes, int n_in,
                              void* d_out, int out_size, void* d_ws, size_t ws_size,
                              hipStream_t stream) {
  const float* x   = (const float*)d_in[0];
  const float* w1  = (const float*)d_in[1];
  const float* b1  = (const float*)d_in[2];
  const float* w2  = (const float*)d_in[3];
  const float* b2  = (const float*)d_in[4];
  const float* w3  = (const float*)d_in[5];
  const float* b3  = (const float*)d_in[6];
  const float* emb = (const float*)d_in[7];
  // decoder weights unused: reference output ignores x_recon

  float* out = (float*)d_out;
  unsigned* wsu = (unsigned*)d_ws;
  unsigned* h1p = wsu + H1P_OFF;
  unsigned* h2p = wsu + H2P_OFF;
  unsigned* wp2 = wsu + WP2_OFF;
  unsigned* wp3 = wsu + WP3_OFF;
  float* enorm = (float*)(wsu + EN_OFF);
  unsigned* hist = wsu + HIST_OFF;
  float* gsse = (float*)(wsu + SSE_OFF);

  hipMemsetAsync(wsu + HIST_OFF, 0, (512 + 1) * sizeof(unsigned), stream);

  pack_w2_k<<<dim3(2048), dim3(256), 0, stream>>>(w2, wp2);
  pack_w3_k<<<dim3(768),  dim3(256), 0, stream>>>(w3, wp3);
  halo_k<<<dim3(9408), dim3(256), 0, stream>>>(h1p, h2p);
  enorm_k<<<dim3(1), dim3(512), 0, stream>>>(emb, enorm);

  conv1_k<<<dim3(8, 8, 16), dim3(16, 16), 0, stream>>>(x, w1, b1, h1p);
  // conv2: 128->256, 4x4 s2 p1 ; in h1p [130][132], out h2p [66][68] packed+ReLU
  convmm_k<128, 16, 256, 130, 132, 2, 68, 4488, 1, true>
      <<<dim3(1024), dim3(256), 0, stream>>>(h1p, wp2, b2, h2p, nullptr);
  // conv3: 256->64, 3x3 s1 p1 (kw padded to 4) ; out fp32 z -> d_out
  convmm_k<256, 12, 64, 66, 68, 1, 64, 4096, 0, false>
      <<<dim3(1024), dim3(256), 0, stream>>>(h2p, wp3, b3, nullptr, out);

  vq_k<<<dim3(256), dim3(256), 0, stream>>>(out, emb, enorm, hist, gsse);
  fin_k<<<dim3(1), dim3(512), 0, stream>>>(hist, gsse, out);
}